// Round 3
// baseline (143.914 us; speedup 1.0000x reference)
//
#include <hip/hip_runtime.h>

#define NB 2
#define NN 1024
#define NROWS (NB*NN)   // 2048 flat rows

#define NEG_INF (-__builtin_huge_valf())

__device__ __forceinline__ float orf(float v, unsigned int m) {
    return __uint_as_float(__float_as_uint(v) | m);
}

// ======================= FUSED persistent kernel =============================
// grid 512 x 256, 2 blocks/CU (LDS 66.8 KB). Three phases + 2 grid barriers.
// Phase A: msg1/msg2/h1 = F@{w1,w2,wo}+b   (4 rows/block)
// Phase B: partial[t][b][j][m] = max_{i in t-range, adj[b,i,j]!=0} msg2[b,i,m]
// Phase C: out = h1 + MLP(relu(msg1 + max_t partial))  (4 rows/block)

union SharedU {
    struct { float sf[4][128]; } a;                                   // 2 KB
    struct { float sm2[128][64]; unsigned int smk[128][68]; } b;      // 66.8 KB
    struct { float sx[4][128]; float sh0[4][32];
             float sh1[4][64]; float sh2[4][64]; } c;                 // 3.5 KB
};

__device__ __forceinline__ void grid_bar(unsigned int* ctr, unsigned int nb) {
    __syncthreads();
    if (threadIdx.x == 0) {
        __threadfence();   // device-scope release of this block's writes
        __hip_atomic_fetch_add(ctr, 1u, __ATOMIC_ACQ_REL, __HIP_MEMORY_SCOPE_AGENT);
        while (__hip_atomic_load(ctr, __ATOMIC_ACQUIRE, __HIP_MEMORY_SCOPE_AGENT) < nb) {
            __builtin_amdgcn_s_sleep(8);
        }
    }
    __syncthreads();
}

__global__ __launch_bounds__(256, 2) void kFused(
    const float* __restrict__ feat, const float* __restrict__ adj,
    const float* __restrict__ w1, const float* __restrict__ b1,
    const float* __restrict__ w2, const float* __restrict__ b2,
    const float* __restrict__ wo, const float* __restrict__ bo,
    const float* __restrict__ wm0, const float* __restrict__ bm0,
    const float* __restrict__ wm1, const float* __restrict__ bm1,
    const float* __restrict__ wm2, const float* __restrict__ bm2,
    const float* __restrict__ wm3, const float* __restrict__ bm3,
    unsigned int* __restrict__ ctr,
    float* __restrict__ msg1, float* __restrict__ msg2, float* __restrict__ h1v,
    float* __restrict__ partial, float* __restrict__ out)
{
    __shared__ SharedU sh;
    const int tid = threadIdx.x;
    const int bid = blockIdx.x;

    // ---------------- Phase A: three linears, 4 rows/block ----------------
    {
        const int rb = bid * 4;
        if (tid < 128) {
            int r = tid >> 5, c = (tid & 31) * 4;
            *reinterpret_cast<float4*>(&sh.a.sf[r][c]) =
                *reinterpret_cast<const float4*>(feat + (size_t)(rb + r)*128 + c);
        }
        __syncthreads();
        const int m = tid & 127, rh = tid >> 7;
        float a1[2] = {0,0}, a2[2] = {0,0}, ao[2] = {0,0};
        #pragma unroll 4
        for (int k = 0; k < 128; ++k) {
            float wv1 = w1[k*128 + m];
            float wv2 = w2[k*128 + m];
            float wvo = wo[k*128 + m];
            #pragma unroll
            for (int r = 0; r < 2; ++r) {
                float f = sh.a.sf[rh*2 + r][k];
                a1[r] = fmaf(f, wv1, a1[r]);
                a2[r] = fmaf(f, wv2, a2[r]);
                ao[r] = fmaf(f, wvo, ao[r]);
            }
        }
        const float bb1 = b1[m], bb2 = b2[m], bbo = bo[m];
        #pragma unroll
        for (int r = 0; r < 2; ++r) {
            size_t row = rb + rh*2 + r;
            msg1[row*128 + m] = a1[r] + bb1;
            msg2[row*128 + m] = a2[r] + bb2;
            h1v [row*128 + m] = ao[r] + bbo;
        }
    }
    grid_bar(ctr + 0, gridDim.x);

    // ---------------- Phase B: masked max over i-range of 128 -------------
    {
        const int jt = bid & 15, it = (bid >> 4) & 7, z = bid >> 7;
        const int mt = z & 1, b = z >> 1;
        const int j0 = jt*64, m0 = mt*64, i0 = it*128;
        const int mg = tid & 7, jl = tid >> 3;

        const float* gp = msg2 + ((size_t)(b*NN + i0))*128 + m0;
        #pragma unroll
        for (int k = 0; k < 8; ++k) {
            int idx = tid + k*256;
            int r = idx >> 4, c = (idx & 15) * 4;
            *reinterpret_cast<float4*>(&sh.b.sm2[r][c]) =
                *reinterpret_cast<const float4*>(gp + (size_t)r*128 + c);
        }
        const float* ga = adj + (size_t)b*NN*NN + (size_t)i0*NN + j0;
        #pragma unroll
        for (int k = 0; k < 8; ++k) {
            int idx = tid + k*256;
            int r = idx >> 4, c = (idx & 15) * 4;
            float4 av = *reinterpret_cast<const float4*>(ga + (size_t)r*NN + c);
            uint4 mk;
            mk.x = (av.x != 0.f) ? 0u : 0xFFC00000u;
            mk.y = (av.y != 0.f) ? 0u : 0xFFC00000u;
            mk.z = (av.z != 0.f) ? 0u : 0xFFC00000u;
            mk.w = (av.w != 0.f) ? 0u : 0xFFC00000u;
            *reinterpret_cast<uint4*>(&sh.b.smk[r][c]) = mk;
        }
        __syncthreads();

        float p0a[8], p1a[8];
        #pragma unroll
        for (int w = 0; w < 8; ++w) { p0a[w] = NEG_INF; p1a[w] = NEG_INF; }
        const float* vr = &sh.b.sm2[0][mg*8];
        const unsigned int* mrA = &sh.b.smk[0][jl];
        const unsigned int* mrB = &sh.b.smk[0][32 + jl];
        #pragma unroll 4
        for (int i = 0; i < 128; i += 2) {
            float4 va = *reinterpret_cast<const float4*>(vr + i*64);
            float4 vb = *reinterpret_cast<const float4*>(vr + i*64 + 4);
            float4 vc = *reinterpret_cast<const float4*>(vr + (i+1)*64);
            float4 vd = *reinterpret_cast<const float4*>(vr + (i+1)*64 + 4);
            unsigned int mA0 = mrA[i*68], mA1 = mrA[(i+1)*68];
            unsigned int mB0 = mrB[i*68], mB1 = mrB[(i+1)*68];
            float v0[8] = {va.x,va.y,va.z,va.w,vb.x,vb.y,vb.z,vb.w};
            float v1[8] = {vc.x,vc.y,vc.z,vc.w,vd.x,vd.y,vd.z,vd.w};
            #pragma unroll
            for (int w = 0; w < 8; ++w) {
                // poisoned operand is quiet NaN -> dropped by IEEE maxnum
                p0a[w] = fmaxf(fmaxf(p0a[w], orf(v0[w], mA0)), orf(v1[w], mA1));
                p1a[w] = fmaxf(fmaxf(p1a[w], orf(v0[w], mB0)), orf(v1[w], mB1));
            }
        }
        float* q0 = partial + ((size_t)(it*2 + b)*NN + (size_t)(j0 + jl))*128 + m0 + mg*8;
        float* q1 = partial + ((size_t)(it*2 + b)*NN + (size_t)(j0 + 32 + jl))*128 + m0 + mg*8;
        *reinterpret_cast<float4*>(q0)     = make_float4(p0a[0],p0a[1],p0a[2],p0a[3]);
        *reinterpret_cast<float4*>(q0 + 4) = make_float4(p0a[4],p0a[5],p0a[6],p0a[7]);
        *reinterpret_cast<float4*>(q1)     = make_float4(p1a[0],p1a[1],p1a[2],p1a[3]);
        *reinterpret_cast<float4*>(q1 + 4) = make_float4(p1a[4],p1a[5],p1a[6],p1a[7]);
    }
    grid_bar(ctr + 1, gridDim.x);

    // ---------------- Phase C: combine + MLP + h1 add, 4 rows/block --------
    {
        const int rb = bid * 4;
        if (tid < 128) {
            int r = tid >> 5, c = (tid & 31) * 4;
            size_t row = rb + r;
            float4 p = make_float4(NEG_INF, NEG_INF, NEG_INF, NEG_INF);
            #pragma unroll
            for (int t = 0; t < 8; ++t) {
                float4 q = *reinterpret_cast<const float4*>(
                    partial + ((size_t)t*NROWS + row)*128 + c);
                p.x = fmaxf(p.x, q.x); p.y = fmaxf(p.y, q.y);
                p.z = fmaxf(p.z, q.z); p.w = fmaxf(p.w, q.w);
            }
            float4 m1 = *reinterpret_cast<const float4*>(msg1 + row*128 + c);
            sh.c.sx[r][c+0] = fmaxf(m1.x + p.x, 0.f);
            sh.c.sx[r][c+1] = fmaxf(m1.y + p.y, 0.f);
            sh.c.sx[r][c+2] = fmaxf(m1.z + p.z, 0.f);
            sh.c.sx[r][c+3] = fmaxf(m1.w + p.w, 0.f);
        }
        __syncthreads();
        if (tid < 128) {   // L0: 128 -> 32
            int r = tid >> 5, c = tid & 31;
            float acc = bm0[c];
            #pragma unroll 8
            for (int k = 0; k < 128; ++k) acc = fmaf(sh.c.sx[r][k], wm0[k*32 + c], acc);
            sh.c.sh0[r][c] = fmaxf(acc, 0.f);
        }
        __syncthreads();
        {   // L1: 32 -> 64
            int r = tid >> 6, c = tid & 63;
            float acc = bm1[c];
            #pragma unroll
            for (int k = 0; k < 32; ++k) acc = fmaf(sh.c.sh0[r][k], wm1[k*64 + c], acc);
            sh.c.sh1[r][c] = fmaxf(acc, 0.f);
        }
        __syncthreads();
        {   // L2: 64 -> 64
            int r = tid >> 6, c = tid & 63;
            float acc = bm2[c];
            #pragma unroll 8
            for (int k = 0; k < 64; ++k) acc = fmaf(sh.c.sh1[r][k], wm2[k*64 + c], acc);
            sh.c.sh2[r][c] = fmaxf(acc, 0.f);
        }
        __syncthreads();
        {   // L3: 64 -> 128, 2 rows/thread, + h1, no relu
            int rq = tid >> 7, c = tid & 127;
            float acc0 = bm3[c], acc1 = bm3[c];
            #pragma unroll 8
            for (int k = 0; k < 64; ++k) {
                float w = wm3[k*128 + c];
                acc0 = fmaf(sh.c.sh2[rq*2][k],   w, acc0);
                acc1 = fmaf(sh.c.sh2[rq*2+1][k], w, acc1);
            }
            size_t r0 = rb + rq*2, r1 = rb + rq*2 + 1;
            out[r0*128 + c] = h1v[r0*128 + c] + acc0;
            out[r1*128 + c] = h1v[r1*128 + c] + acc1;
        }
    }
}

// ======================= Fallback 3-kernel path (small ws) ===================
__global__ __launch_bounds__(256) void kA_lin3(
    const float* __restrict__ feat,
    const float* __restrict__ w1, const float* __restrict__ b1,
    const float* __restrict__ w2, const float* __restrict__ b2,
    const float* __restrict__ wo, const float* __restrict__ bo,
    float* __restrict__ msg1, float* __restrict__ msg2, float* __restrict__ h1)
{
    __shared__ float sf[8][128];
    const int tid = threadIdx.x;
    const int rb = blockIdx.x * 8;
    {
        int r = tid >> 5, c = (tid & 31) * 4;
        *reinterpret_cast<float4*>(&sf[r][c]) =
            *reinterpret_cast<const float4*>(feat + (size_t)(rb + r) * 128 + c);
    }
    __syncthreads();
    const int m = tid & 127, rh = tid >> 7;
    float a1[4] = {0,0,0,0}, a2[4] = {0,0,0,0}, ao[4] = {0,0,0,0};
    #pragma unroll 4
    for (int k = 0; k < 128; ++k) {
        float wv1 = w1[k*128 + m], wv2 = w2[k*128 + m], wvo = wo[k*128 + m];
        #pragma unroll
        for (int r = 0; r < 4; ++r) {
            float f = sf[rh*4 + r][k];
            a1[r] = fmaf(f, wv1, a1[r]);
            a2[r] = fmaf(f, wv2, a2[r]);
            ao[r] = fmaf(f, wvo, ao[r]);
        }
    }
    const float bb1 = b1[m], bb2 = b2[m], bbo = bo[m];
    #pragma unroll
    for (int r = 0; r < 4; ++r) {
        size_t row = rb + rh*4 + r;
        msg1[row*128 + m] = a1[r] + bb1;
        msg2[row*128 + m] = a2[r] + bb2;
        h1  [row*128 + m] = ao[r] + bbo;
    }
}

__global__ __launch_bounds__(256) void kB_maxred1(
    const float* __restrict__ adj, const float* __restrict__ msg2,
    float* __restrict__ partial)
{
    __shared__ float sm2[128][64];
    __shared__ unsigned int smk[128][68];
    const int tid = threadIdx.x;
    const int jt = blockIdx.x;
    const int mt = blockIdx.z & 1, b = blockIdx.z >> 1;
    const int j0 = jt * 64, m0 = mt * 64;
    const int mg = tid & 7, jl = tid >> 3;
    float a0[8], a1[8];
    #pragma unroll
    for (int w = 0; w < 8; ++w) { a0[w] = NEG_INF; a1[w] = NEG_INF; }
    for (int ic = 0; ic < NN; ic += 128) {
        if (ic) __syncthreads();
        const float* gp = msg2 + ((size_t)(b*NN + ic))*128 + m0;
        #pragma unroll
        for (int k = 0; k < 8; ++k) {
            int idx = tid + k*256;
            int r = idx >> 4, c = (idx & 15) * 4;
            *reinterpret_cast<float4*>(&sm2[r][c]) =
                *reinterpret_cast<const float4*>(gp + (size_t)r*128 + c);
        }
        const float* ga = adj + (size_t)b*NN*NN + (size_t)ic*NN + j0;
        #pragma unroll
        for (int k = 0; k < 8; ++k) {
            int idx = tid + k*256;
            int r = idx >> 4, c = (idx & 15) * 4;
            float4 av = *reinterpret_cast<const float4*>(ga + (size_t)r*NN + c);
            uint4 mk;
            mk.x = (av.x != 0.f) ? 0u : 0xFFC00000u;
            mk.y = (av.y != 0.f) ? 0u : 0xFFC00000u;
            mk.z = (av.z != 0.f) ? 0u : 0xFFC00000u;
            mk.w = (av.w != 0.f) ? 0u : 0xFFC00000u;
            *reinterpret_cast<uint4*>(&smk[r][c]) = mk;
        }
        __syncthreads();
        const float* vr = &sm2[0][mg*8];
        const unsigned int* mrA = &smk[0][jl];
        const unsigned int* mrB = &smk[0][32 + jl];
        #pragma unroll 4
        for (int i = 0; i < 128; i += 2) {
            float4 va = *reinterpret_cast<const float4*>(vr + i*64);
            float4 vb = *reinterpret_cast<const float4*>(vr + i*64 + 4);
            float4 vc = *reinterpret_cast<const float4*>(vr + (i+1)*64);
            float4 vd = *reinterpret_cast<const float4*>(vr + (i+1)*64 + 4);
            unsigned int mA0 = mrA[i*68], mA1 = mrA[(i+1)*68];
            unsigned int mB0 = mrB[i*68], mB1 = mrB[(i+1)*68];
            float v0[8] = {va.x,va.y,va.z,va.w,vb.x,vb.y,vb.z,vb.w};
            float v1[8] = {vc.x,vc.y,vc.z,vc.w,vd.x,vd.y,vd.z,vd.w};
            #pragma unroll
            for (int w = 0; w < 8; ++w) {
                a0[w] = fmaxf(fmaxf(a0[w], orf(v0[w], mA0)), orf(v1[w], mA1));
                a1[w] = fmaxf(fmaxf(a1[w], orf(v0[w], mB0)), orf(v1[w], mB1));
            }
        }
    }
    float* p0 = partial + ((size_t)b*NN + (size_t)(j0 + jl))*128 + m0 + mg*8;
    float* p1 = partial + ((size_t)b*NN + (size_t)(j0 + 32 + jl))*128 + m0 + mg*8;
    *reinterpret_cast<float4*>(p0)     = make_float4(a0[0],a0[1],a0[2],a0[3]);
    *reinterpret_cast<float4*>(p0 + 4) = make_float4(a0[4],a0[5],a0[6],a0[7]);
    *reinterpret_cast<float4*>(p1)     = make_float4(a1[0],a1[1],a1[2],a1[3]);
    *reinterpret_cast<float4*>(p1 + 4) = make_float4(a1[4],a1[5],a1[6],a1[7]);
}

__global__ __launch_bounds__(256) void kC_mlp1(
    const float* __restrict__ msg1, const float* __restrict__ h1,
    const float* __restrict__ partial,
    const float* __restrict__ wm0, const float* __restrict__ bm0,
    const float* __restrict__ wm1, const float* __restrict__ bm1,
    const float* __restrict__ wm2, const float* __restrict__ bm2,
    const float* __restrict__ wm3, const float* __restrict__ bm3,
    float* __restrict__ out)
{
    __shared__ float sx[4][128];
    __shared__ float sh0[4][32];
    __shared__ float sh1[4][64];
    __shared__ float sh2[4][64];
    const int tid = threadIdx.x;
    const int rb = blockIdx.x * 4;
    if (tid < 128) {
        int r = tid >> 5, c = (tid & 31) * 4;
        size_t row = rb + r;
        float4 p = *reinterpret_cast<const float4*>(partial + row*128 + c);
        float4 m1 = *reinterpret_cast<const float4*>(msg1 + row*128 + c);
        sx[r][c+0] = fmaxf(m1.x + p.x, 0.f);
        sx[r][c+1] = fmaxf(m1.y + p.y, 0.f);
        sx[r][c+2] = fmaxf(m1.z + p.z, 0.f);
        sx[r][c+3] = fmaxf(m1.w + p.w, 0.f);
    }
    __syncthreads();
    if (tid < 128) {
        int r = tid >> 5, c = tid & 31;
        float acc = bm0[c];
        #pragma unroll 8
        for (int k = 0; k < 128; ++k) acc = fmaf(sx[r][k], wm0[k*32 + c], acc);
        sh0[r][c] = fmaxf(acc, 0.f);
    }
    __syncthreads();
    {
        int r = tid >> 6, c = tid & 63;
        float acc = bm1[c];
        #pragma unroll
        for (int k = 0; k < 32; ++k) acc = fmaf(sh0[r][k], wm1[k*64 + c], acc);
        sh1[r][c] = fmaxf(acc, 0.f);
    }
    __syncthreads();
    {
        int r = tid >> 6, c = tid & 63;
        float acc = bm2[c];
        #pragma unroll 8
        for (int k = 0; k < 64; ++k) acc = fmaf(sh1[r][k], wm2[k*64 + c], acc);
        sh2[r][c] = fmaxf(acc, 0.f);
    }
    __syncthreads();
    {
        int rq = tid >> 7, c = tid & 127;
        float acc0 = bm3[c], acc1 = bm3[c];
        #pragma unroll 8
        for (int k = 0; k < 64; ++k) {
            float w = wm3[k*128 + c];
            acc0 = fmaf(sh2[rq*2][k],   w, acc0);
            acc1 = fmaf(sh2[rq*2+1][k], w, acc1);
        }
        size_t r0 = rb + rq*2, r1 = rb + rq*2 + 1;
        out[r0*128 + c] = h1[r0*128 + c] + acc0;
        out[r1*128 + c] = h1[r1*128 + c] + acc1;
    }
}

extern "C" void kernel_launch(void* const* d_in, const int* in_sizes, int n_in,
                              void* d_out, int out_size, void* d_ws, size_t ws_size,
                              hipStream_t stream)
{
    const float* feat = (const float*)d_in[0];
    // d_in[1] = e_features (unused), d_in[2] = g_features (unused)
    const float* adj  = (const float*)d_in[3];
    const float* w1 = (const float*)d_in[4];   const float* b1 = (const float*)d_in[5];
    const float* w2 = (const float*)d_in[6];   const float* b2 = (const float*)d_in[7];
    const float* wo = (const float*)d_in[8];   const float* bo = (const float*)d_in[9];
    const float* wm0 = (const float*)d_in[10]; const float* bm0 = (const float*)d_in[11];
    const float* wm1 = (const float*)d_in[12]; const float* bm1 = (const float*)d_in[13];
    const float* wm2 = (const float*)d_in[14]; const float* bm2 = (const float*)d_in[15];
    const float* wm3 = (const float*)d_in[16]; const float* bm3 = (const float*)d_in[17];
    float* out = (float*)d_out;

    const size_t MAT = (size_t)NROWS * 128;   // 262144 floats
    unsigned int* ctr = (unsigned int*)d_ws;
    float* base = (float*)((char*)d_ws + 256);
    float* msg1 = base;
    float* msg2 = base + MAT;
    float* h1v  = base + 2*MAT;
    float* partial = base + 3*MAT;

    const size_t need_fused = 256 + (3 + 8) * MAT * sizeof(float);
    if (ws_size >= need_fused) {
        hipMemsetAsync(d_ws, 0, 256, stream);   // reset barrier counters
        kFused<<<512, 256, 0, stream>>>(feat, adj,
            w1,b1,w2,b2,wo,bo, wm0,bm0,wm1,bm1,wm2,bm2,wm3,bm3,
            ctr, msg1, msg2, h1v, partial, out);
    } else {
        // fallback: 3 kernels, single partial slot
        kA_lin3<<<256, 256, 0, stream>>>(feat, w1, b1, w2, b2, wo, bo, msg1, msg2, h1v);
        dim3 gb(16, 1, 4);
        kB_maxred1<<<gb, 256, 0, stream>>>(adj, msg2, partial);
        kC_mlp1<<<512, 256, 0, stream>>>(msg1, h1v, partial,
            wm0,bm0,wm1,bm1,wm2,bm2,wm3,bm3, out);
    }
}

// Round 4
// 133.222 us; speedup vs baseline: 1.0803x; 1.0803x over previous
//
#include <hip/hip_runtime.h>

#define NB 2
#define NN 1024
#define NROWS (NB*NN)   // 2048 flat rows

#define NEG_INF (-__builtin_huge_valf())

__device__ __forceinline__ float orf(float v, unsigned int m) {
    return __uint_as_float(__float_as_uint(v) | m);
}

// ---------------- Kernel 1: msg1 = F@w1+b1 ; msg2 = F@w2+b2 ; h1 = F@wo+bo ---
// grid 512 x 256; 4 rows/block (2 blocks/CU).
__global__ __launch_bounds__(256) void kA_lin3(
    const float* __restrict__ feat,
    const float* __restrict__ w1, const float* __restrict__ b1,
    const float* __restrict__ w2, const float* __restrict__ b2,
    const float* __restrict__ wo, const float* __restrict__ bo,
    float* __restrict__ msg1, float* __restrict__ msg2, float* __restrict__ h1)
{
    __shared__ float sf[4][128];
    const int tid = threadIdx.x;
    const int rb = blockIdx.x * 4;
    if (tid < 128) {
        int r = tid >> 5, c = (tid & 31) * 4;
        *reinterpret_cast<float4*>(&sf[r][c]) =
            *reinterpret_cast<const float4*>(feat + (size_t)(rb + r) * 128 + c);
    }
    __syncthreads();
    const int m = tid & 127, rh = tid >> 7;
    float a1[2] = {0,0}, a2[2] = {0,0}, ao[2] = {0,0};
    #pragma unroll 4
    for (int k = 0; k < 128; ++k) {
        float wv1 = w1[k*128 + m], wv2 = w2[k*128 + m], wvo = wo[k*128 + m];
        #pragma unroll
        for (int r = 0; r < 2; ++r) {
            float f = sf[rh*2 + r][k];
            a1[r] = fmaf(f, wv1, a1[r]);
            a2[r] = fmaf(f, wv2, a2[r]);
            ao[r] = fmaf(f, wvo, ao[r]);
        }
    }
    const float bb1 = b1[m], bb2 = b2[m], bbo = bo[m];
    #pragma unroll
    for (int r = 0; r < 2; ++r) {
        size_t row = rb + rh*2 + r;
        msg1[row*128 + m] = a1[r] + bb1;
        msg2[row*128 + m] = a2[r] + bb2;
        h1  [row*128 + m] = ao[r] + bbo;
    }
}

// ---------------- Kernel 2: masked max partials + last-arriver MLP finish ----
// grid (jt=16, it=8, z=4: mt=z&1, b=z>>1), block 256, 2 blocks/CU.
// B: partial[it][b][j][m-half] = max_{i in it-range, adj!=0} msg2[i][m]
// then atomicAdd ctr[jt*2+b]; the 16th arriver (8 it x 2 mt) runs phase C
// (combine partials + relu + MLP + h1 add) for rows (b, j0..j0+64).
union SharedU {
    struct { float sm2[128][64]; unsigned int smk[128][68]; } b;  // 66.8 KB
    struct { float sx[64][132]; float sh0[64][36];
             float sh1[64][68]; float sh2[64][68]; } c;           // ~71 KB
};

__global__ __launch_bounds__(256, 2) void kBC(
    const float* __restrict__ adj, const float* __restrict__ msg2,
    const float* __restrict__ msg1, const float* __restrict__ h1v,
    const float* __restrict__ wm0, const float* __restrict__ bm0,
    const float* __restrict__ wm1, const float* __restrict__ bm1,
    const float* __restrict__ wm2, const float* __restrict__ bm2,
    const float* __restrict__ wm3, const float* __restrict__ bm3,
    unsigned int* __restrict__ ctr,
    float* __restrict__ partial, float* __restrict__ out)
{
    __shared__ SharedU sh;
    __shared__ int fin;
    const int tid = threadIdx.x;
    const int jt = blockIdx.x, it = blockIdx.y;
    const int mt = blockIdx.z & 1, b = blockIdx.z >> 1;
    const int j0 = jt*64, m0 = mt*64, i0 = it*128;

    // ---- Phase B ----
    {
        const int mg = tid & 7, jl = tid >> 3;
        const float* gp = msg2 + ((size_t)(b*NN + i0))*128 + m0;
        #pragma unroll
        for (int k = 0; k < 8; ++k) {
            int idx = tid + k*256;
            int r = idx >> 4, c = (idx & 15) * 4;
            *reinterpret_cast<float4*>(&sh.b.sm2[r][c]) =
                *reinterpret_cast<const float4*>(gp + (size_t)r*128 + c);
        }
        const float* ga = adj + (size_t)b*NN*NN + (size_t)i0*NN + j0;
        #pragma unroll
        for (int k = 0; k < 8; ++k) {
            int idx = tid + k*256;
            int r = idx >> 4, c = (idx & 15) * 4;
            float4 av = *reinterpret_cast<const float4*>(ga + (size_t)r*NN + c);
            uint4 mk;
            mk.x = (av.x != 0.f) ? 0u : 0xFFC00000u;
            mk.y = (av.y != 0.f) ? 0u : 0xFFC00000u;
            mk.z = (av.z != 0.f) ? 0u : 0xFFC00000u;
            mk.w = (av.w != 0.f) ? 0u : 0xFFC00000u;
            *reinterpret_cast<uint4*>(&sh.b.smk[r][c]) = mk;
        }
        __syncthreads();

        float a0[8], a1[8];
        #pragma unroll
        for (int w = 0; w < 8; ++w) { a0[w] = NEG_INF; a1[w] = NEG_INF; }
        const float* vr = &sh.b.sm2[0][mg*8];
        const unsigned int* mrA = &sh.b.smk[0][jl];
        const unsigned int* mrB = &sh.b.smk[0][32 + jl];
        #pragma unroll 4
        for (int i = 0; i < 128; i += 2) {
            float4 va = *reinterpret_cast<const float4*>(vr + i*64);
            float4 vb = *reinterpret_cast<const float4*>(vr + i*64 + 4);
            float4 vc = *reinterpret_cast<const float4*>(vr + (i+1)*64);
            float4 vd = *reinterpret_cast<const float4*>(vr + (i+1)*64 + 4);
            unsigned int mA0 = mrA[i*68], mA1 = mrA[(i+1)*68];
            unsigned int mB0 = mrB[i*68], mB1 = mrB[(i+1)*68];
            float v0[8] = {va.x,va.y,va.z,va.w,vb.x,vb.y,vb.z,vb.w};
            float v1[8] = {vc.x,vc.y,vc.z,vc.w,vd.x,vd.y,vd.z,vd.w};
            #pragma unroll
            for (int w = 0; w < 8; ++w) {
                // poisoned operand is quiet NaN -> dropped by IEEE maxnum
                a0[w] = fmaxf(fmaxf(a0[w], orf(v0[w], mA0)), orf(v1[w], mA1));
                a1[w] = fmaxf(fmaxf(a1[w], orf(v0[w], mB0)), orf(v1[w], mB1));
            }
        }
        float* q0 = partial + ((size_t)(it*2 + b)*NN + (size_t)(j0 + jl))*128 + m0 + mg*8;
        float* q1 = partial + ((size_t)(it*2 + b)*NN + (size_t)(j0 + 32 + jl))*128 + m0 + mg*8;
        *reinterpret_cast<float4*>(q0)     = make_float4(a0[0],a0[1],a0[2],a0[3]);
        *reinterpret_cast<float4*>(q0 + 4) = make_float4(a0[4],a0[5],a0[6],a0[7]);
        *reinterpret_cast<float4*>(q1)     = make_float4(a1[0],a1[1],a1[2],a1[3]);
        *reinterpret_cast<float4*>(q1 + 4) = make_float4(a1[4],a1[5],a1[6],a1[7]);
    }

    // ---- Completion signal: no spin, last arriver continues ----
    __threadfence();          // release this block's partial stores agent-wide
    __syncthreads();
    if (tid == 0) {
        unsigned int old = __hip_atomic_fetch_add(&ctr[jt*2 + b], 1u,
                             __ATOMIC_ACQ_REL, __HIP_MEMORY_SCOPE_AGENT);
        fin = (old == 15);    // 8 it x 2 mt contributors
    }
    __syncthreads();
    if (!fin) return;
    __threadfence();          // acquire: see all contributors' partial stores

    // ---- Phase C: 64 rows (b, j0..j0+64) ----
    const size_t rowbase = (size_t)b*NN + j0;
    __syncthreads();          // LDS union reuse: everyone past B reads
    // sx = relu(msg1 + max_it partial)
    #pragma unroll
    for (int t = 0; t < 8; ++t) {
        int e = tid + t*256;
        int r = e >> 5, c = (e & 31) * 4;
        float4 p = make_float4(NEG_INF, NEG_INF, NEG_INF, NEG_INF);
        #pragma unroll
        for (int s = 0; s < 8; ++s) {
            float4 q = *reinterpret_cast<const float4*>(
                partial + ((size_t)(s*2 + b)*NN + j0 + r)*128 + c);
            p.x = fmaxf(p.x, q.x); p.y = fmaxf(p.y, q.y);
            p.z = fmaxf(p.z, q.z); p.w = fmaxf(p.w, q.w);
        }
        float4 m1 = *reinterpret_cast<const float4*>(msg1 + (rowbase + r)*128 + c);
        float4 v;
        v.x = fmaxf(m1.x + p.x, 0.f); v.y = fmaxf(m1.y + p.y, 0.f);
        v.z = fmaxf(m1.z + p.z, 0.f); v.w = fmaxf(m1.w + p.w, 0.f);
        *reinterpret_cast<float4*>(&sh.c.sx[r][c]) = v;
    }
    __syncthreads();
    {   // L0: 128->32. thread: c=tid&31, rg=tid>>5 -> 8 rows. b128 k-chunks.
        const int c = tid & 31, rg = tid >> 5;
        float acc[8];
        const float bb = bm0[c];
        #pragma unroll
        for (int r = 0; r < 8; ++r) acc[r] = bb;
        for (int k = 0; k < 128; k += 4) {
            float w0 = wm0[(k+0)*32 + c], w1_ = wm0[(k+1)*32 + c];
            float w2_ = wm0[(k+2)*32 + c], w3 = wm0[(k+3)*32 + c];
            #pragma unroll
            for (int r = 0; r < 8; ++r) {
                float4 x = *reinterpret_cast<const float4*>(&sh.c.sx[rg*8 + r][k]);
                acc[r] = fmaf(x.x, w0, acc[r]);
                acc[r] = fmaf(x.y, w1_, acc[r]);
                acc[r] = fmaf(x.z, w2_, acc[r]);
                acc[r] = fmaf(x.w, w3, acc[r]);
            }
        }
        #pragma unroll
        for (int r = 0; r < 8; ++r) sh.c.sh0[rg*8 + r][c] = fmaxf(acc[r], 0.f);
    }
    __syncthreads();
    {   // L1: 32->64. thread: cg=tid&31 -> 2 cols, rg=tid>>5 -> 8 rows.
        const int cg = tid & 31, rg = tid >> 5;
        const int c = cg*2;
        float acc[8][2];
        const float b0 = bm1[c], b1_ = bm1[c+1];
        #pragma unroll
        for (int r = 0; r < 8; ++r) { acc[r][0] = b0; acc[r][1] = b1_; }
        for (int k = 0; k < 32; k += 4) {
            float wA[4], wB[4];
            #pragma unroll
            for (int kk = 0; kk < 4; ++kk) {
                wA[kk] = wm1[(k+kk)*64 + c];
                wB[kk] = wm1[(k+kk)*64 + c + 1];
            }
            #pragma unroll
            for (int r = 0; r < 8; ++r) {
                float4 x = *reinterpret_cast<const float4*>(&sh.c.sh0[rg*8 + r][k]);
                const float* xp = reinterpret_cast<const float*>(&x);
                #pragma unroll
                for (int kk = 0; kk < 4; ++kk) {
                    acc[r][0] = fmaf(xp[kk], wA[kk], acc[r][0]);
                    acc[r][1] = fmaf(xp[kk], wB[kk], acc[r][1]);
                }
            }
        }
        #pragma unroll
        for (int r = 0; r < 8; ++r) {
            sh.c.sh1[rg*8 + r][c]   = fmaxf(acc[r][0], 0.f);
            sh.c.sh1[rg*8 + r][c+1] = fmaxf(acc[r][1], 0.f);
        }
    }
    __syncthreads();
    {   // L2: 64->64. same shape as L1 but k=64.
        const int cg = tid & 31, rg = tid >> 5;
        const int c = cg*2;
        float acc[8][2];
        const float b0 = bm2[c], b1_ = bm2[c+1];
        #pragma unroll
        for (int r = 0; r < 8; ++r) { acc[r][0] = b0; acc[r][1] = b1_; }
        for (int k = 0; k < 64; k += 4) {
            float wA[4], wB[4];
            #pragma unroll
            for (int kk = 0; kk < 4; ++kk) {
                wA[kk] = wm2[(k+kk)*64 + c];
                wB[kk] = wm2[(k+kk)*64 + c + 1];
            }
            #pragma unroll
            for (int r = 0; r < 8; ++r) {
                float4 x = *reinterpret_cast<const float4*>(&sh.c.sh1[rg*8 + r][k]);
                const float* xp = reinterpret_cast<const float*>(&x);
                #pragma unroll
                for (int kk = 0; kk < 4; ++kk) {
                    acc[r][0] = fmaf(xp[kk], wA[kk], acc[r][0]);
                    acc[r][1] = fmaf(xp[kk], wB[kk], acc[r][1]);
                }
            }
        }
        #pragma unroll
        for (int r = 0; r < 8; ++r) {
            sh.c.sh2[rg*8 + r][c]   = fmaxf(acc[r][0], 0.f);
            sh.c.sh2[rg*8 + r][c+1] = fmaxf(acc[r][1], 0.f);
        }
    }
    __syncthreads();
    {   // L3: 64->128, + h1, no relu. thread: cg=tid&31 -> 4 cols, rg=tid>>5 -> 8 rows.
        const int cg = tid & 31, rg = tid >> 5;
        const int c = cg*4;
        float acc[8][4];
        #pragma unroll
        for (int r = 0; r < 8; ++r) {
            acc[r][0] = bm3[c]; acc[r][1] = bm3[c+1];
            acc[r][2] = bm3[c+2]; acc[r][3] = bm3[c+3];
        }
        for (int k = 0; k < 64; k += 4) {
            float4 wq[4];
            #pragma unroll
            for (int kk = 0; kk < 4; ++kk)
                wq[kk] = *reinterpret_cast<const float4*>(wm3 + (k+kk)*128 + c);
            #pragma unroll
            for (int r = 0; r < 8; ++r) {
                float4 x = *reinterpret_cast<const float4*>(&sh.c.sh2[rg*8 + r][k]);
                const float* xp = reinterpret_cast<const float*>(&x);
                #pragma unroll
                for (int kk = 0; kk < 4; ++kk) {
                    acc[r][0] = fmaf(xp[kk], wq[kk].x, acc[r][0]);
                    acc[r][1] = fmaf(xp[kk], wq[kk].y, acc[r][1]);
                    acc[r][2] = fmaf(xp[kk], wq[kk].z, acc[r][2]);
                    acc[r][3] = fmaf(xp[kk], wq[kk].w, acc[r][3]);
                }
            }
        }
        #pragma unroll
        for (int r = 0; r < 8; ++r) {
            size_t row = rowbase + rg*8 + r;
            float4 hh = *reinterpret_cast<const float4*>(h1v + row*128 + c);
            float4 o;
            o.x = hh.x + acc[r][0]; o.y = hh.y + acc[r][1];
            o.z = hh.z + acc[r][2]; o.w = hh.w + acc[r][3];
            *reinterpret_cast<float4*>(out + row*128 + c) = o;
        }
    }
}

extern "C" void kernel_launch(void* const* d_in, const int* in_sizes, int n_in,
                              void* d_out, int out_size, void* d_ws, size_t ws_size,
                              hipStream_t stream)
{
    const float* feat = (const float*)d_in[0];
    // d_in[1] = e_features (unused), d_in[2] = g_features (unused)
    const float* adj  = (const float*)d_in[3];
    const float* w1 = (const float*)d_in[4];   const float* b1 = (const float*)d_in[5];
    const float* w2 = (const float*)d_in[6];   const float* b2 = (const float*)d_in[7];
    const float* wo = (const float*)d_in[8];   const float* bo = (const float*)d_in[9];
    const float* wm0 = (const float*)d_in[10]; const float* bm0 = (const float*)d_in[11];
    const float* wm1 = (const float*)d_in[12]; const float* bm1 = (const float*)d_in[13];
    const float* wm2 = (const float*)d_in[14]; const float* bm2 = (const float*)d_in[15];
    const float* wm3 = (const float*)d_in[16]; const float* bm3 = (const float*)d_in[17];
    float* out = (float*)d_out;

    const size_t MAT = (size_t)NROWS * 128;   // 262144 floats
    unsigned int* ctr = (unsigned int*)d_ws;
    float* base = (float*)((char*)d_ws + 256);
    float* msg1 = base;
    float* msg2 = base + MAT;
    float* h1v  = base + 2*MAT;
    float* partial = base + 3*MAT;

    // reset the 32 finisher counters (graph-capturable)
    hipMemsetAsync(d_ws, 0, 256, stream);

    kA_lin3<<<512, 256, 0, stream>>>(feat, w1, b1, w2, b2, wo, bo, msg1, msg2, h1v);

    dim3 gb(16, 8, 4);
    kBC<<<gb, 256, 0, stream>>>(adj, msg2, msg1, h1v,
        wm0,bm0,wm1,bm1,wm2,bm2,wm3,bm3, ctr, partial, out);
}

// Round 5
// 49.552 us; speedup vs baseline: 2.9043x; 2.6885x over previous
//
#include <hip/hip_runtime.h>

#define NB 2
#define NN 1024
#define NROWS (NB*NN)   // 2048 flat rows

#define NEG_INF (-__builtin_huge_valf())

__device__ __forceinline__ float orf(float v, unsigned int m) {
    return __uint_as_float(__float_as_uint(v) | m);
}

// ---------------- Kernel A: msg1 = F@w1+b1 ; msg2 = F@w2+b2 ; h1 = F@wo+bo ---
// grid 256 x 512; 8 rows/block. Weight streams L2-resident (192 KB/block).
__global__ __launch_bounds__(512) void kA_lin3(
    const float* __restrict__ feat,
    const float* __restrict__ w1, const float* __restrict__ b1,
    const float* __restrict__ w2, const float* __restrict__ b2,
    const float* __restrict__ wo, const float* __restrict__ bo,
    float* __restrict__ msg1, float* __restrict__ msg2, float* __restrict__ h1)
{
    __shared__ float sf[8][128];
    const int tid = threadIdx.x;
    const int rb = blockIdx.x * 8;
    if (tid < 256) {
        int r = tid >> 5, c = (tid & 31) * 4;
        *reinterpret_cast<float4*>(&sf[r][c]) =
            *reinterpret_cast<const float4*>(feat + (size_t)(rb + r) * 128 + c);
    }
    __syncthreads();
    const int m = tid & 127, rh = tid >> 7;   // rh 0..3 -> rows rh*2, rh*2+1
    float a1[2] = {0,0}, a2[2] = {0,0}, ao[2] = {0,0};
    #pragma unroll 4
    for (int k = 0; k < 128; ++k) {
        float wv1 = w1[k*128 + m], wv2 = w2[k*128 + m], wvo = wo[k*128 + m];
        #pragma unroll
        for (int r = 0; r < 2; ++r) {
            float f = sf[rh*2 + r][k];
            a1[r] = fmaf(f, wv1, a1[r]);
            a2[r] = fmaf(f, wv2, a2[r]);
            ao[r] = fmaf(f, wvo, ao[r]);
        }
    }
    const float bb1 = b1[m], bb2 = b2[m], bbo = bo[m];
    #pragma unroll
    for (int r = 0; r < 2; ++r) {
        size_t row = rb + rh*2 + r;
        msg1[row*128 + m] = a1[r] + bb1;
        msg2[row*128 + m] = a2[r] + bb2;
        h1  [row*128 + m] = ao[r] + bbo;
    }
}

// ---------------- Kernel B: partial masked max over i-range of 128 -----------
// partial[it][b][j][m-half] = max_{i in range, adj[b,i,j]!=0} msg2[b,i,m]
// grid (jt=16, it=8, z=4: mt=z&1, b=z>>1), block 256, 2 blocks/CU.
// Thread: mg=tid&7 -> 8 m; jq=(tid>>3)&15 -> 4 j (jq+16*jj); ih=tid>>7 -> i-half.
// Masks: packed nibbles (u16 per (i-pair, jq)); expand in VALU; or+max3 update.
struct BShared {
    float sm2[128][64];                 // 32 KB  [i][m]
    union {
        float sadjf[128][68];           // 34.8 KB staged adj floats (pad 68)
        float scratch[32][132];         // 16.9 KB cross-ih combine (after pack)
    } u;
    unsigned short smkb2[64][16];       // 2 KB   [i-pair][jq] bit-nibbles
};

__global__ __launch_bounds__(256, 2) void kB_maxred(
    const float* __restrict__ adj, const float* __restrict__ msg2,
    float* __restrict__ partial)
{
    __shared__ BShared sh;
    const int tid = threadIdx.x;
    const int jt = blockIdx.x, it = blockIdx.y;
    const int mt = blockIdx.z & 1, b = blockIdx.z >> 1;
    const int j0 = jt*64, m0 = mt*64, i0 = it*128;

    // stage msg2 tile [128][64]
    {
        const float* gp = msg2 + ((size_t)(b*NN + i0))*128 + m0;
        #pragma unroll
        for (int k = 0; k < 8; ++k) {
            int idx = tid + k*256;
            int r = idx >> 4, c = (idx & 15) * 4;
            *reinterpret_cast<float4*>(&sh.sm2[r][c]) =
                *reinterpret_cast<const float4*>(gp + (size_t)r*128 + c);
        }
    }
    // stage adj floats [128][64] (raw copy)
    {
        const float* ga = adj + (size_t)b*NN*NN + (size_t)i0*NN + j0;
        #pragma unroll
        for (int k = 0; k < 8; ++k) {
            int idx = tid + k*256;
            int r = idx >> 4, c = (idx & 15) * 4;
            *reinterpret_cast<float4*>(&sh.u.sadjf[r][c]) =
                *reinterpret_cast<const float4*>(ga + (size_t)r*NN + c);
        }
    }
    __syncthreads();
    // pack: u16 per (i-pair, jq): bits 0..3 = even i, jj=0..3; bits 8..11 = odd i
    #pragma unroll
    for (int t = 0; t < 4; ++t) {
        int e = tid + t*256;          // 0..1023
        int ip = e >> 4, jq_ = e & 15;
        unsigned int bits = 0;
        #pragma unroll
        for (int k = 0; k < 4; ++k) {
            bits |= (sh.u.sadjf[2*ip  ][jq_ + 16*k] != 0.f) ? (1u << k)       : 0u;
            bits |= (sh.u.sadjf[2*ip+1][jq_ + 16*k] != 0.f) ? (1u << (k + 8)) : 0u;
        }
        sh.smkb2[ip][jq_] = (unsigned short)bits;
    }
    __syncthreads();

    const int mg = tid & 7;
    const int jq = (tid >> 3) & 15;
    const int ih = tid >> 7;
    const float* vr = &sh.sm2[0][mg*8];
    const unsigned short* mk = &sh.smkb2[0][jq];

    float acc[4][8];
    #pragma unroll
    for (int jj = 0; jj < 4; ++jj)
        #pragma unroll
        for (int w = 0; w < 8; ++w) acc[jj][w] = NEG_INF;

    const int pbase = ih * 32;        // 32 i-pairs per half
    #pragma unroll 4
    for (int p = 0; p < 32; ++p) {
        const int i = (pbase + p) * 2;
        float4 va = *reinterpret_cast<const float4*>(vr + i*64);
        float4 vb = *reinterpret_cast<const float4*>(vr + i*64 + 4);
        float4 vc = *reinterpret_cast<const float4*>(vr + (i+1)*64);
        float4 vd = *reinterpret_cast<const float4*>(vr + (i+1)*64 + 4);
        unsigned int bb = mk[(pbase + p)*16];
        float v0[8] = {va.x,va.y,va.z,va.w,vb.x,vb.y,vb.z,vb.w};
        float v1[8] = {vc.x,vc.y,vc.z,vc.w,vd.x,vd.y,vd.z,vd.w};
        #pragma unroll
        for (int jj = 0; jj < 4; ++jj) {
            unsigned int k0 = (((bb >> jj)       & 1u) - 1u) & 0xFFC00000u;
            unsigned int k1 = (((bb >> (jj + 8)) & 1u) - 1u) & 0xFFC00000u;
            #pragma unroll
            for (int w = 0; w < 8; ++w) {
                // poisoned operand is quiet NaN -> dropped by IEEE maxnum (max3)
                acc[jj][w] = fmaxf(fmaxf(acc[jj][w], orf(v0[w], k0)), orf(v1[w], k1));
            }
        }
    }

    // cross-ih combine: ih=1 publishes to scratch (overlays sadjf, dead region);
    // no barrier needed before writes (nobody reads sadjf after pack-sync).
    if (ih == 1) {
        const int t = tid - 128;
        #pragma unroll
        for (int jj = 0; jj < 4; ++jj)
            #pragma unroll
            for (int w = 0; w < 8; ++w)
                sh.u.scratch[jj*8 + w][t] = acc[jj][w];
    }
    __syncthreads();
    if (ih == 0) {
        #pragma unroll
        for (int jj = 0; jj < 4; ++jj) {
            float r[8];
            #pragma unroll
            for (int w = 0; w < 8; ++w)
                r[w] = fmaxf(acc[jj][w], sh.u.scratch[jj*8 + w][tid]);
            const int j = j0 + jq + 16*jj;
            float* q = partial + ((size_t)(it*2 + b)*NN + j)*128 + m0 + mg*8;
            *reinterpret_cast<float4*>(q)     = make_float4(r[0], r[1], r[2], r[3]);
            *reinterpret_cast<float4*>(q + 4) = make_float4(r[4], r[5], r[6], r[7]);
        }
    }
}

// ---------------- Kernel C: combine partials + relu + MLP + h1 add -----------
// grid 512 x 256; 4 rows/block.
__global__ __launch_bounds__(256) void kC_mlp(
    const float* __restrict__ msg1, const float* __restrict__ h1,
    const float* __restrict__ partial,
    const float* __restrict__ wm0, const float* __restrict__ bm0,
    const float* __restrict__ wm1, const float* __restrict__ bm1,
    const float* __restrict__ wm2, const float* __restrict__ bm2,
    const float* __restrict__ wm3, const float* __restrict__ bm3,
    float* __restrict__ out)
{
    __shared__ float sx[4][128];
    __shared__ float sh0[4][32];
    __shared__ float sh1[4][64];
    __shared__ float sh2[4][64];
    const int tid = threadIdx.x;
    const int rb = blockIdx.x * 4;

    if (tid < 128) {
        int r = tid >> 5, c = (tid & 31) * 4;
        size_t row = rb + r;
        float4 p = make_float4(NEG_INF, NEG_INF, NEG_INF, NEG_INF);
        #pragma unroll
        for (int t = 0; t < 8; ++t) {
            float4 q = *reinterpret_cast<const float4*>(
                partial + ((size_t)t*NROWS + row)*128 + c);
            p.x = fmaxf(p.x, q.x); p.y = fmaxf(p.y, q.y);
            p.z = fmaxf(p.z, q.z); p.w = fmaxf(p.w, q.w);
        }
        float4 m1 = *reinterpret_cast<const float4*>(msg1 + row*128 + c);
        sx[r][c+0] = fmaxf(m1.x + p.x, 0.f);   // -inf propagates -> relu 0
        sx[r][c+1] = fmaxf(m1.y + p.y, 0.f);
        sx[r][c+2] = fmaxf(m1.z + p.z, 0.f);
        sx[r][c+3] = fmaxf(m1.w + p.w, 0.f);
    }
    __syncthreads();
    if (tid < 128) {   // L0: 128 -> 32
        int r = tid >> 5, c = tid & 31;
        float acc = bm0[c];
        #pragma unroll 8
        for (int k = 0; k < 128; ++k) acc = fmaf(sx[r][k], wm0[k*32 + c], acc);
        sh0[r][c] = fmaxf(acc, 0.f);
    }
    __syncthreads();
    {   // L1: 32 -> 64
        int r = tid >> 6, c = tid & 63;
        float acc = bm1[c];
        #pragma unroll
        for (int k = 0; k < 32; ++k) acc = fmaf(sh0[r][k], wm1[k*64 + c], acc);
        sh1[r][c] = fmaxf(acc, 0.f);
    }
    __syncthreads();
    {   // L2: 64 -> 64
        int r = tid >> 6, c = tid & 63;
        float acc = bm2[c];
        #pragma unroll 8
        for (int k = 0; k < 64; ++k) acc = fmaf(sh1[r][k], wm2[k*64 + c], acc);
        sh2[r][c] = fmaxf(acc, 0.f);
    }
    __syncthreads();
    {   // L3: 64 -> 128, 2 rows/thread, + h1, no relu
        int rq = tid >> 7, c = tid & 127;
        float acc0 = bm3[c], acc1 = bm3[c];
        #pragma unroll 8
        for (int k = 0; k < 64; ++k) {
            float w = wm3[k*128 + c];
            acc0 = fmaf(sh2[rq*2][k],   w, acc0);
            acc1 = fmaf(sh2[rq*2+1][k], w, acc1);
        }
        size_t r0 = rb + rq*2, r1 = rb + rq*2 + 1;
        out[r0*128 + c] = h1[r0*128 + c] + acc0;
        out[r1*128 + c] = h1[r1*128 + c] + acc1;
    }
}

extern "C" void kernel_launch(void* const* d_in, const int* in_sizes, int n_in,
                              void* d_out, int out_size, void* d_ws, size_t ws_size,
                              hipStream_t stream)
{
    const float* feat = (const float*)d_in[0];
    // d_in[1] = e_features (unused), d_in[2] = g_features (unused)
    const float* adj  = (const float*)d_in[3];
    const float* w1 = (const float*)d_in[4];   const float* b1 = (const float*)d_in[5];
    const float* w2 = (const float*)d_in[6];   const float* b2 = (const float*)d_in[7];
    const float* wo = (const float*)d_in[8];   const float* bo = (const float*)d_in[9];
    const float* wm0 = (const float*)d_in[10]; const float* bm0 = (const float*)d_in[11];
    const float* wm1 = (const float*)d_in[12]; const float* bm1 = (const float*)d_in[13];
    const float* wm2 = (const float*)d_in[14]; const float* bm2 = (const float*)d_in[15];
    const float* wm3 = (const float*)d_in[16]; const float* bm3 = (const float*)d_in[17];
    float* out = (float*)d_out;

    const size_t MAT = (size_t)NROWS * 128;   // 262144 floats
    float* base = (float*)d_ws;
    float* msg1 = base;
    float* msg2 = base + MAT;
    float* h1v  = base + 2*MAT;
    float* partial = base + 3*MAT;            // 8 it-slices x NROWS x 128

    kA_lin3<<<256, 512, 0, stream>>>(feat, w1, b1, w2, b2, wo, bo, msg1, msg2, h1v);

    dim3 gb(16, 8, 4);
    kB_maxred<<<gb, 256, 0, stream>>>(adj, msg2, partial);

    kC_mlp<<<512, 256, 0, stream>>>(msg1, h1v, partial,
        wm0,bm0,wm1,bm1,wm2,bm2,wm3,bm3, out);
}